// Round 1
// baseline (171.304 us; speedup 1.0000x reference)
//
#include <hip/hip_runtime.h>
#include <cstdint>
#include <cstddef>

#define NB 4
#define NS 2048
#define ND 512
#define NH 8
#define DH 64
#define MTOK (NB*NS)

typedef __bf16 bf16x8 __attribute__((ext_vector_type(8)));
typedef float f32x4 __attribute__((ext_vector_type(4)));
typedef unsigned short ushort_t;
typedef unsigned int uint_t;

__device__ __forceinline__ unsigned short f2bf(float f) {
  unsigned int u = __builtin_bit_cast(unsigned int, f);
  return (unsigned short)((u + 0x7fffu + ((u >> 16) & 1u)) >> 16);
}

__device__ __forceinline__ void gload_lds16(const void* g, void* l) {
  __builtin_amdgcn_global_load_lds(
      (const __attribute__((address_space(1))) unsigned int*)g,
      (__attribute__((address_space(3))) unsigned int*)l,
      16, 0, 0);
}

// ---------------- LayerNorm: fp32 x -> bf16 xn, one wave per row ----------------
__global__ __launch_bounds__(256) void ln_kernel(
    const float* __restrict__ x, const float* __restrict__ gamma,
    const float* __restrict__ beta, ushort_t* __restrict__ xn)
{
  const int row  = blockIdx.x * 4 + (threadIdx.x >> 6);
  const int lane = threadIdx.x & 63;
  const float4* xr = (const float4*)(x + (size_t)row * ND);
  float4 a = xr[lane*2], b = xr[lane*2+1];
  float v[8] = {a.x,a.y,a.z,a.w,b.x,b.y,b.z,b.w};
  float s = 0.f, s2 = 0.f;
#pragma unroll
  for (int j = 0; j < 8; ++j) { s += v[j]; s2 += v[j]*v[j]; }
#pragma unroll
  for (int mk = 1; mk < 64; mk <<= 1) { s += __shfl_xor(s, mk); s2 += __shfl_xor(s2, mk); }
  const float mu = s * (1.0f/ND);
  const float rs = rsqrtf(s2*(1.0f/ND) - mu*mu + 1e-5f);
  const float4* g4 = (const float4*)gamma;
  const float4* b4 = (const float4*)beta;
  float4 g0 = g4[lane*2], g1 = g4[lane*2+1];
  float4 e0 = b4[lane*2], e1 = b4[lane*2+1];
  float gv[8] = {g0.x,g0.y,g0.z,g0.w,g1.x,g1.y,g1.z,g1.w};
  float ev[8] = {e0.x,e0.y,e0.z,e0.w,e1.x,e1.y,e1.z,e1.w};
  unsigned short o[8];
#pragma unroll
  for (int j = 0; j < 8; ++j) o[j] = f2bf((v[j]-mu)*rs*gv[j] + ev[j]);
  uint4 ov;
  ov.x = (uint_t)o[0] | ((uint_t)o[1]<<16);
  ov.y = (uint_t)o[2] | ((uint_t)o[3]<<16);
  ov.z = (uint_t)o[4] | ((uint_t)o[5]<<16);
  ov.w = (uint_t)o[6] | ((uint_t)o[7]<<16);
  ((uint4*)(xn + (size_t)row*ND))[lane] = ov;
}

// ---------------- weight conversion: Wq/Wk/Wv -> wqkv[1536][512] bf16, Wo -> bf16 ----------------
__global__ __launch_bounds__(256) void convert_w(
    const float* __restrict__ Wq, const float* __restrict__ Wk,
    const float* __restrict__ Wv, const float* __restrict__ Wo,
    ushort_t* __restrict__ wqkv, ushort_t* __restrict__ wob)
{
  const int t = blockIdx.x*256 + threadIdx.x;
  const int i = t*8;
  const float* src; ushort_t* dst;
  if (i < 1536*512) {
    const int n = i >> 9, c = i & 511;
    const float* W = (n < 512) ? Wq : (n < 1024) ? Wk : Wv;
    src = W + ((size_t)(n & 511) << 9) + c;
    dst = wqkv + i;
  } else {
    const int jj = i - 1536*512;
    src = Wo + jj; dst = wob + jj;
  }
  float4 a = ((const float4*)src)[0], b = ((const float4*)src)[1];
  uint4 o;
  o.x = (uint_t)f2bf(a.x) | ((uint_t)f2bf(a.y)<<16);
  o.y = (uint_t)f2bf(a.z) | ((uint_t)f2bf(a.w)<<16);
  o.z = (uint_t)f2bf(b.x) | ((uint_t)f2bf(b.y)<<16);
  o.w = (uint_t)f2bf(b.z) | ((uint_t)f2bf(b.w)<<16);
  *(uint4*)dst = o;
}

// ---------------- GEMM C[M,N] = A[M,K] * Bw[N,K]^T, 128x128 tile, BK=32 ----------------
// EPI==0: QKV epilogue (bias + scatter to q/k/vt, Q scaled by 0.125)
// EPI==1: output projection epilogue (bias, fp32 store)
template<int EPI>
__global__ __launch_bounds__(256, 2) void gemm_bt(
    const ushort_t* __restrict__ A, const ushort_t* __restrict__ Bw, int Kd,
    const float* __restrict__ bq, const float* __restrict__ bk, const float* __restrict__ bv,
    ushort_t* __restrict__ qa, ushort_t* __restrict__ ka, ushort_t* __restrict__ vta,
    const float* __restrict__ bo, float* __restrict__ outp)
{
  __shared__ ushort_t lA[128*32];
  __shared__ ushort_t lB[128*32];
  const int tid = threadIdx.x;
  const int wave = tid >> 6, lane = tid & 63;
  const int m0 = blockIdx.y * 128, n0 = blockIdx.x * 128;
  const int wr = (wave >> 1) * 64, wc = (wave & 1) * 64;

  f32x4 acc[4][4] = {};

  const ushort_t* aS = A  + (size_t)(m0 + tid/4) * Kd + (tid & 3) * 8;
  const ushort_t* bS = Bw + (size_t)(n0 + tid/4) * Kd + (tid & 3) * 8;
  const size_t half = (size_t)64 * Kd;

  for (int k0 = 0; k0 < Kd; k0 += 32) {
    __syncthreads();
    gload_lds16(aS + k0,        lA + wave*512);
    gload_lds16(aS + half + k0, lA + 2048 + wave*512);
    gload_lds16(bS + k0,        lB + wave*512);
    gload_lds16(bS + half + k0, lB + 2048 + wave*512);
    __syncthreads();
    bf16x8 af[4], bfr[4];
#pragma unroll
    for (int i = 0; i < 4; ++i)
      af[i] = *(const bf16x8*)(lA + (wr + i*16 + (lane&15))*32 + (lane>>4)*8);
#pragma unroll
    for (int j = 0; j < 4; ++j)
      bfr[j] = *(const bf16x8*)(lB + (wc + j*16 + (lane&15))*32 + (lane>>4)*8);
#pragma unroll
    for (int i = 0; i < 4; ++i)
#pragma unroll
      for (int j = 0; j < 4; ++j)
        acc[i][j] = __builtin_amdgcn_mfma_f32_16x16x32_bf16(af[i], bfr[j], acc[i][j], 0, 0, 0);
  }

  if (EPI == 0) {
#pragma unroll
    for (int j = 0; j < 4; ++j) {
      const int n = n0 + wc + j*16 + (lane & 15);
      if (n < 512) {
        const float bb = bq[n]; const int h = n >> 6, d = n & 63;
#pragma unroll
        for (int i = 0; i < 4; ++i)
#pragma unroll
          for (int r = 0; r < 4; ++r) {
            const int m = m0 + wr + i*16 + 4*(lane>>4) + r;
            const int b = m >> 11, s = m & 2047;
            qa[(((size_t)(b*NH + h))*NS + s)*DH + d] = f2bf((acc[i][j][r] + bb) * 0.125f);
          }
      } else if (n < 1024) {
        const int nn = n - 512;
        const float bb = bk[nn]; const int h = nn >> 6, d = nn & 63;
#pragma unroll
        for (int i = 0; i < 4; ++i)
#pragma unroll
          for (int r = 0; r < 4; ++r) {
            const int m = m0 + wr + i*16 + 4*(lane>>4) + r;
            const int b = m >> 11, s = m & 2047;
            ka[(((size_t)(b*NH + h))*NS + s)*DH + d] = f2bf(acc[i][j][r] + bb);
          }
      } else {
        const int nn = n - 1024;
        const float bb = bv[nn]; const int h = nn >> 6, d = nn & 63;
#pragma unroll
        for (int i = 0; i < 4; ++i)
#pragma unroll
          for (int r = 0; r < 4; ++r) {
            const int m = m0 + wr + i*16 + 4*(lane>>4) + r;
            const int b = m >> 11, s = m & 2047;
            vta[(((size_t)(b*NH + h))*DH + d)*NS + s] = f2bf(acc[i][j][r] + bb);
          }
      }
    }
  } else {
#pragma unroll
    for (int j = 0; j < 4; ++j) {
      const int n = n0 + wc + j*16 + (lane & 15);
      const float bb = bo[n];
#pragma unroll
      for (int i = 0; i < 4; ++i)
#pragma unroll
        for (int r = 0; r < 4; ++r) {
          const int m = m0 + wr + i*16 + 4*(lane>>4) + r;
          outp[(size_t)m*ND + n] = acc[i][j][r] + bb;
        }
    }
  }
}

// ---------------- flash attention: 1 block = 64 Q rows of one (b,h) ----------------
__global__ __launch_bounds__(256, 2) void attn_kernel(
    const ushort_t* __restrict__ q, const ushort_t* __restrict__ kA,
    const ushort_t* __restrict__ vt, ushort_t* __restrict__ ao)
{
  const int bh = blockIdx.y;
  const int q0 = blockIdx.x * 64;
  const int tid = threadIdx.x;
  const int wave = tid >> 6, lane = tid & 63;

  __shared__ ushort_t lK[64*88];      // [kv_row][64+pad]
  __shared__ ushort_t lV[64*88];      // [d][64+pad] (V^T tile)
  __shared__ ushort_t lP[4][16*88];   // per-wave P transpose buffer

  const ushort_t* qB = q + ((size_t)bh * NS + q0 + wave*16 + (lane&15)) * DH + (lane>>4)*8;
  bf16x8 qf0 = *(const bf16x8*)(qB);
  bf16x8 qf1 = *(const bf16x8*)(qB + 32);

  f32x4 o[4] = {};
  float mrow[4], lrow[4];
#pragma unroll
  for (int r = 0; r < 4; ++r) { mrow[r] = -1e30f; lrow[r] = 0.f; }

  const ushort_t* kB = kA + (size_t)bh * NS * DH;
  const ushort_t* vB = vt + (size_t)bh * DH * NS;
  const int sr = tid >> 3, ss = tid & 7;

  for (int j0 = 0; j0 < NS; j0 += 64) {
    __syncthreads();
#pragma unroll
    for (int p = 0; p < 2; ++p) {
      const int r = sr + p*32;
      *(uint4*)(lK + r*88 + ss*8) = *(const uint4*)(kB + (size_t)(j0 + r)*DH + ss*8);
      *(uint4*)(lV + r*88 + ss*8) = *(const uint4*)(vB + (size_t)r*NS + j0 + ss*8);
    }
    __syncthreads();

    f32x4 sc[4];
#pragma unroll
    for (int t = 0; t < 4; ++t) {
      const ushort_t* kp = lK + (t*16 + (lane&15))*88 + (lane>>4)*8;
      f32x4 c = {};
      c = __builtin_amdgcn_mfma_f32_16x16x32_bf16(qf0, *(const bf16x8*)kp,      c, 0,0,0);
      c = __builtin_amdgcn_mfma_f32_16x16x32_bf16(qf1, *(const bf16x8*)(kp+32), c, 0,0,0);
      sc[t] = c;
    }

    float pm[4];
#pragma unroll
    for (int r = 0; r < 4; ++r)
      pm[r] = fmaxf(fmaxf(sc[0][r], sc[1][r]), fmaxf(sc[2][r], sc[3][r]));
#pragma unroll
    for (int mk = 1; mk <= 8; mk <<= 1)
#pragma unroll
      for (int r = 0; r < 4; ++r) pm[r] = fmaxf(pm[r], __shfl_xor(pm[r], mk));

    float fac[4], rsum[4];
    unsigned short pb[4][4];
#pragma unroll
    for (int r = 0; r < 4; ++r) {
      const float mn = fmaxf(mrow[r], pm[r]);
      fac[r] = __expf(mrow[r] - mn);
      mrow[r] = mn;
      rsum[r] = 0.f;
    }
#pragma unroll
    for (int t = 0; t < 4; ++t)
#pragma unroll
      for (int r = 0; r < 4; ++r) {
        const float p = __expf(sc[t][r] - mrow[r]);
        rsum[r] += p;
        pb[t][r] = f2bf(p);
      }
#pragma unroll
    for (int mk = 1; mk <= 8; mk <<= 1)
#pragma unroll
      for (int r = 0; r < 4; ++r) rsum[r] += __shfl_xor(rsum[r], mk);
#pragma unroll
    for (int r = 0; r < 4; ++r) lrow[r] = lrow[r]*fac[r] + rsum[r];
#pragma unroll
    for (int t = 0; t < 4; ++t) {
      f32x4 tmp = o[t];
#pragma unroll
      for (int r = 0; r < 4; ++r) tmp[r] *= fac[r];
      o[t] = tmp;
    }
#pragma unroll
    for (int t = 0; t < 4; ++t)
#pragma unroll
      for (int r = 0; r < 4; ++r)
        lP[wave][(4*(lane>>4)+r)*88 + t*16 + (lane&15)] = pb[t][r];
    __syncthreads();

    const ushort_t* pp = lP[wave] + (lane&15)*88 + (lane>>4)*8;
    bf16x8 pf0 = *(const bf16x8*)pp;
    bf16x8 pf1 = *(const bf16x8*)(pp + 32);
#pragma unroll
    for (int t = 0; t < 4; ++t) {
      const ushort_t* vp = lV + (t*16 + (lane&15))*88 + (lane>>4)*8;
      o[t] = __builtin_amdgcn_mfma_f32_16x16x32_bf16(pf0, *(const bf16x8*)vp,      o[t], 0,0,0);
      o[t] = __builtin_amdgcn_mfma_f32_16x16x32_bf16(pf1, *(const bf16x8*)(vp+32), o[t], 0,0,0);
    }
  }

  const int b = bh >> 3, h = bh & 7;
#pragma unroll
  for (int t = 0; t < 4; ++t)
#pragma unroll
    for (int r = 0; r < 4; ++r) {
      const int srow = q0 + wave*16 + 4*(lane>>4) + r;
      ao[((size_t)(b*NS + srow))*ND + h*DH + t*16 + (lane&15)] = f2bf(o[t][r] / lrow[r]);
    }
}

extern "C" void kernel_launch(void* const* d_in, const int* in_sizes, int n_in,
                              void* d_out, int out_size, void* d_ws, size_t ws_size,
                              hipStream_t stream)
{
  const float* x  = (const float*)d_in[0];
  const float* g  = (const float*)d_in[1];
  const float* be = (const float*)d_in[2];
  const float* Wq = (const float*)d_in[3];
  const float* bq = (const float*)d_in[4];
  const float* Wk = (const float*)d_in[5];
  const float* bk = (const float*)d_in[6];
  const float* Wv = (const float*)d_in[7];
  const float* bv = (const float*)d_in[8];
  const float* Wo = (const float*)d_in[9];
  const float* bo = (const float*)d_in[10];
  float* out = (float*)d_out;

  char* w = (char*)d_ws;
  ushort_t* xn   = (ushort_t*)w; w += (size_t)MTOK*ND*2;
  ushort_t* wqkv = (ushort_t*)w; w += (size_t)1536*512*2;
  ushort_t* wob  = (ushort_t*)w; w += (size_t)512*512*2;
  ushort_t* qa   = (ushort_t*)w; w += (size_t)MTOK*ND*2;
  ushort_t* ka   = (ushort_t*)w; w += (size_t)MTOK*ND*2;
  ushort_t* vta  = (ushort_t*)w; w += (size_t)MTOK*ND*2;
  ushort_t* ao   = (ushort_t*)w; w += (size_t)MTOK*ND*2;

  ln_kernel<<<MTOK/4, 256, 0, stream>>>(x, g, be, xn);
  convert_w<<<512, 256, 0, stream>>>(Wq, Wk, Wv, Wo, wqkv, wob);
  gemm_bt<0><<<dim3(12, 64), 256, 0, stream>>>(xn, wqkv, ND,
      bq, bk, bv, qa, ka, vta, nullptr, nullptr);
  attn_kernel<<<dim3(NS/64, NB*NH), 256, 0, stream>>>(qa, ka, vta, ao);
  gemm_bt<1><<<dim3(4, 64), 256, 0, stream>>>(ao, wob, ND,
      nullptr, nullptr, nullptr, nullptr, nullptr, nullptr, bo, out);
}

// Round 2
// 169.031 us; speedup vs baseline: 1.0134x; 1.0134x over previous
//
#include <hip/hip_runtime.h>
#include <cstdint>
#include <cstddef>

#define NB 4
#define NS 2048
#define ND 512
#define NH 8
#define DH 64
#define MTOK (NB*NS)

typedef __bf16 bf16x8 __attribute__((ext_vector_type(8)));
typedef float f32x4 __attribute__((ext_vector_type(4)));
typedef float f32x16 __attribute__((ext_vector_type(16)));
typedef unsigned int u32x4 __attribute__((ext_vector_type(4)));
typedef unsigned short ushort_t;
typedef unsigned int uint_t;

__device__ __forceinline__ unsigned short f2bf(float f) {
  unsigned int u = __builtin_bit_cast(unsigned int, f);
  return (unsigned short)((u + 0x7fffu + ((u >> 16) & 1u)) >> 16);
}

__device__ __forceinline__ uint_t cvtpk(float lo, float hi) {
  uint_t r;
  asm("v_cvt_pk_bf16_f32 %0, %1, %2" : "=v"(r) : "v"(lo), "v"(hi));
  return r;
}

// swap lanes 32-63 of a with lanes 0-31 of b
__device__ __forceinline__ void pswap(uint_t &a, uint_t &b) {
  asm("v_permlane32_swap_b32 %0, %1" : "+v"(a), "+v"(b));
}

__device__ __forceinline__ void gload_lds16(const void* g, void* l) {
  __builtin_amdgcn_global_load_lds(
      (const __attribute__((address_space(1))) unsigned int*)g,
      (__attribute__((address_space(3))) unsigned int*)l,
      16, 0, 0);
}

__device__ __forceinline__ bf16x8 ld8(const ushort_t* p) { return *(const bf16x8*)p; }

// ---------------- LayerNorm: fp32 x -> bf16 xn, one wave per row ----------------
__global__ __launch_bounds__(256) void ln_kernel(
    const float* __restrict__ x, const float* __restrict__ gamma,
    const float* __restrict__ beta, ushort_t* __restrict__ xn)
{
  const int row  = blockIdx.x * 4 + (threadIdx.x >> 6);
  const int lane = threadIdx.x & 63;
  const float4* xr = (const float4*)(x + (size_t)row * ND);
  float4 a = xr[lane*2], b = xr[lane*2+1];
  float v[8] = {a.x,a.y,a.z,a.w,b.x,b.y,b.z,b.w};
  float s = 0.f, s2 = 0.f;
#pragma unroll
  for (int j = 0; j < 8; ++j) { s += v[j]; s2 += v[j]*v[j]; }
#pragma unroll
  for (int mk = 1; mk < 64; mk <<= 1) { s += __shfl_xor(s, mk); s2 += __shfl_xor(s2, mk); }
  const float mu = s * (1.0f/ND);
  const float rs = rsqrtf(s2*(1.0f/ND) - mu*mu + 1e-5f);
  const float4* g4 = (const float4*)gamma;
  const float4* b4 = (const float4*)beta;
  float4 g0 = g4[lane*2], g1 = g4[lane*2+1];
  float4 e0 = b4[lane*2], e1 = b4[lane*2+1];
  float gv[8] = {g0.x,g0.y,g0.z,g0.w,g1.x,g1.y,g1.z,g1.w};
  float ev[8] = {e0.x,e0.y,e0.z,e0.w,e1.x,e1.y,e1.z,e1.w};
  unsigned short o[8];
#pragma unroll
  for (int j = 0; j < 8; ++j) o[j] = f2bf((v[j]-mu)*rs*gv[j] + ev[j]);
  uint4 ov;
  ov.x = (uint_t)o[0] | ((uint_t)o[1]<<16);
  ov.y = (uint_t)o[2] | ((uint_t)o[3]<<16);
  ov.z = (uint_t)o[4] | ((uint_t)o[5]<<16);
  ov.w = (uint_t)o[6] | ((uint_t)o[7]<<16);
  ((uint4*)(xn + (size_t)row*ND))[lane] = ov;
}

// ---------------- weight conversion ----------------
__global__ __launch_bounds__(256) void convert_w(
    const float* __restrict__ Wq, const float* __restrict__ Wk,
    const float* __restrict__ Wv, const float* __restrict__ Wo,
    ushort_t* __restrict__ wqkv, ushort_t* __restrict__ wob)
{
  const int t = blockIdx.x*256 + threadIdx.x;
  const int i = t*8;
  const float* src; ushort_t* dst;
  if (i < 1536*512) {
    const int n = i >> 9, c = i & 511;
    const float* W = (n < 512) ? Wq : (n < 1024) ? Wk : Wv;
    src = W + ((size_t)(n & 511) << 9) + c;
    dst = wqkv + i;
  } else {
    const int jj = i - 1536*512;
    src = Wo + jj; dst = wob + jj;
  }
  float4 a = ((const float4*)src)[0], b = ((const float4*)src)[1];
  uint4 o;
  o.x = (uint_t)f2bf(a.x) | ((uint_t)f2bf(a.y)<<16);
  o.y = (uint_t)f2bf(a.z) | ((uint_t)f2bf(a.w)<<16);
  o.z = (uint_t)f2bf(b.x) | ((uint_t)f2bf(b.y)<<16);
  o.w = (uint_t)f2bf(b.z) | ((uint_t)f2bf(b.w)<<16);
  *(uint4*)dst = o;
}

// ---------------- GEMM C[M,N] = A[M,K] * Bw[N,K]^T, 128x128 tile, BK=32 ----------------
template<int EPI>
__global__ __launch_bounds__(256, 2) void gemm_bt(
    const ushort_t* __restrict__ A, const ushort_t* __restrict__ Bw, int Kd,
    const float* __restrict__ bq, const float* __restrict__ bk, const float* __restrict__ bv,
    ushort_t* __restrict__ qa, ushort_t* __restrict__ ka, ushort_t* __restrict__ vta,
    const float* __restrict__ bo, float* __restrict__ outp)
{
  __shared__ ushort_t lA[128*32];
  __shared__ ushort_t lB[128*32];
  const int tid = threadIdx.x;
  const int wave = tid >> 6, lane = tid & 63;
  const int m0 = blockIdx.y * 128, n0 = blockIdx.x * 128;
  const int wr = (wave >> 1) * 64, wc = (wave & 1) * 64;

  f32x4 acc[4][4] = {};

  const ushort_t* aS = A  + (size_t)(m0 + tid/4) * Kd + (tid & 3) * 8;
  const ushort_t* bS = Bw + (size_t)(n0 + tid/4) * Kd + (tid & 3) * 8;
  const size_t half = (size_t)64 * Kd;

  for (int k0 = 0; k0 < Kd; k0 += 32) {
    __syncthreads();
    gload_lds16(aS + k0,        lA + wave*512);
    gload_lds16(aS + half + k0, lA + 2048 + wave*512);
    gload_lds16(bS + k0,        lB + wave*512);
    gload_lds16(bS + half + k0, lB + 2048 + wave*512);
    __syncthreads();
    bf16x8 af[4], bfr[4];
#pragma unroll
    for (int i = 0; i < 4; ++i)
      af[i] = *(const bf16x8*)(lA + (wr + i*16 + (lane&15))*32 + (lane>>4)*8);
#pragma unroll
    for (int j = 0; j < 4; ++j)
      bfr[j] = *(const bf16x8*)(lB + (wc + j*16 + (lane&15))*32 + (lane>>4)*8);
#pragma unroll
    for (int i = 0; i < 4; ++i)
#pragma unroll
      for (int j = 0; j < 4; ++j)
        acc[i][j] = __builtin_amdgcn_mfma_f32_16x16x32_bf16(af[i], bfr[j], acc[i][j], 0, 0, 0);
  }

  if (EPI == 0) {
    // Q scaled by Dh^-0.5 * log2(e) so attention softmax can run in base 2
    const float QSCALE = 0.18033688011112042f;
#pragma unroll
    for (int j = 0; j < 4; ++j) {
      const int n = n0 + wc + j*16 + (lane & 15);
      if (n < 512) {
        const float bb = bq[n]; const int h = n >> 6, d = n & 63;
#pragma unroll
        for (int i = 0; i < 4; ++i)
#pragma unroll
          for (int r = 0; r < 4; ++r) {
            const int m = m0 + wr + i*16 + 4*(lane>>4) + r;
            const int b = m >> 11, s = m & 2047;
            qa[(((size_t)(b*NH + h))*NS + s)*DH + d] = f2bf((acc[i][j][r] + bb) * QSCALE);
          }
      } else if (n < 1024) {
        const int nn = n - 512;
        const float bb = bk[nn]; const int h = nn >> 6, d = nn & 63;
#pragma unroll
        for (int i = 0; i < 4; ++i)
#pragma unroll
          for (int r = 0; r < 4; ++r) {
            const int m = m0 + wr + i*16 + 4*(lane>>4) + r;
            const int b = m >> 11, s = m & 2047;
            ka[(((size_t)(b*NH + h))*NS + s)*DH + d] = f2bf(acc[i][j][r] + bb);
          }
      } else {
        const int nn = n - 1024;
        const float bb = bv[nn]; const int h = nn >> 6, d = nn & 63;
#pragma unroll
        for (int i = 0; i < 4; ++i)
#pragma unroll
          for (int r = 0; r < 4; ++r) {
            const int m = m0 + wr + i*16 + 4*(lane>>4) + r;
            const int b = m >> 11, s = m & 2047;
            vta[(((size_t)(b*NH + h))*DH + d)*NS + s] = f2bf(acc[i][j][r] + bb);
          }
      }
    }
  } else {
#pragma unroll
    for (int j = 0; j < 4; ++j) {
      const int n = n0 + wc + j*16 + (lane & 15);
      const float bb = bo[n];
#pragma unroll
      for (int i = 0; i < 4; ++i)
#pragma unroll
        for (int r = 0; r < 4; ++r) {
          const int m = m0 + wr + i*16 + 4*(lane>>4) + r;
          outp[(size_t)m*ND + n] = acc[i][j][r] + bb;
        }
    }
  }
}

// ---------------- flash attention, swapped-operand 32x32x16, no LDS, no barriers ----
// block = 4 waves x 32 q rows = 128 q rows of one (b,h). KV tile = 64.
// S^T = mfma(K,Q): lane&31 = q, regs = kv.  O^T = mfma(V^T,P): lane&31 = q, regs = d.
__global__ __launch_bounds__(256) void attn_kernel(
    const ushort_t* __restrict__ q, const ushort_t* __restrict__ kA,
    const ushort_t* __restrict__ vt, ushort_t* __restrict__ ao)
{
  // XCD-bijective swizzle: bits [2:0]=bh_low, [6:3]=qblk, [8:7]=bh_high
  const int blk = blockIdx.x;
  const int bh   = (blk & 7) | ((blk >> 7) << 3);
  const int qblk = (blk >> 3) & 15;
  const int w    = threadIdx.x >> 6;
  const int lane = threadIdx.x & 63;
  const int lo5 = lane & 31, hi = lane >> 5;

  const size_t bhNS = (size_t)bh * NS;
  const ushort_t* qptr = q  + (bhNS + qblk*128 + w*32 + lo5) * DH + hi*8;
  const ushort_t* kptr = kA + bhNS * DH + (size_t)lo5 * DH + hi*8;
  const ushort_t* vptr = vt + (size_t)bh * DH * NS + (size_t)lo5 * NS + hi*8;

  bf16x8 qf[4];
#pragma unroll
  for (int s = 0; s < 4; ++s) qf[s] = ld8(qptr + 16*s);

  f32x16 o0 = {}, o1 = {};
  float m = -1e30f, l = 0.f;

  bf16x8 kf0[4], kf1[4];
#pragma unroll
  for (int s = 0; s < 4; ++s) { kf0[s] = ld8(kptr + 16*s); kf1[s] = ld8(kptr + 32*DH + 16*s); }

  for (int j0 = 0; j0 < NS; j0 += 64) {
    // ---- QK^T (swapped): sc[kv, q] ----
    f32x16 s0 = {}, s1 = {};
#pragma unroll
    for (int s = 0; s < 4; ++s) {
      s0 = __builtin_amdgcn_mfma_f32_32x32x16_bf16(kf0[s], qf[s], s0, 0, 0, 0);
      s1 = __builtin_amdgcn_mfma_f32_32x32x16_bf16(kf1[s], qf[s], s1, 0, 0, 0);
    }
    // ---- V fragments for this tile (latency hides under softmax) ----
    bf16x8 vf0[4], vf1[4];
#pragma unroll
    for (int ks = 0; ks < 4; ++ks) {
      vf0[ks] = ld8(vptr + j0 + 16*ks);
      vf1[ks] = ld8(vptr + (size_t)32*NS + j0 + 16*ks);
    }
    // ---- prefetch K for next tile ----
    if (j0 + 64 < NS) {
      const ushort_t* kn = kptr + (size_t)(j0 + 64) * DH;
#pragma unroll
      for (int s = 0; s < 4; ++s) { kf0[s] = ld8(kn + 16*s); kf1[s] = ld8(kn + 32*DH + 16*s); }
    }
    // ---- online softmax (base 2), fully lane-local ----
    float mloc = s0[0];
#pragma unroll
    for (int r = 1; r < 16; ++r) mloc = fmaxf(mloc, s0[r]);
#pragma unroll
    for (int r = 0; r < 16; ++r) mloc = fmaxf(mloc, s1[r]);
    mloc = fmaxf(mloc, __shfl_xor(mloc, 32));
    if (__any(mloc > m + 8.0f)) {          // defer-max (T13), wave-uniform branch
      const float mn  = fmaxf(m, mloc);
      const float fac = __builtin_amdgcn_exp2f(m - mn);
      m = mn; l *= fac;
#pragma unroll
      for (int r = 0; r < 16; ++r) { o0[r] *= fac; o1[r] *= fac; }
    }
    float p0[16], p1[16];
    float rs = 0.f;
#pragma unroll
    for (int r = 0; r < 16; ++r) { p0[r] = __builtin_amdgcn_exp2f(s0[r] - m); rs += p0[r]; }
#pragma unroll
    for (int r = 0; r < 16; ++r) { p1[r] = __builtin_amdgcn_exp2f(s1[r] - m); rs += p1[r]; }
    rs += __shfl_xor(rs, 32);
    l += rs;
    // ---- P -> B-fragments in-register (cvt_pk + permlane32_swap) ----
    bf16x8 pf[4];
    {
      uint_t a, b, c, d;
      a = cvtpk(p0[0],  p0[1]);  b = cvtpk(p0[4],  p0[5]);  pswap(a, b);
      c = cvtpk(p0[2],  p0[3]);  d = cvtpk(p0[6],  p0[7]);  pswap(c, d);
      pf[0] = __builtin_bit_cast(bf16x8, (u32x4){a, c, b, d});
      a = cvtpk(p0[8],  p0[9]);  b = cvtpk(p0[12], p0[13]); pswap(a, b);
      c = cvtpk(p0[10], p0[11]); d = cvtpk(p0[14], p0[15]); pswap(c, d);
      pf[1] = __builtin_bit_cast(bf16x8, (u32x4){a, c, b, d});
      a = cvtpk(p1[0],  p1[1]);  b = cvtpk(p1[4],  p1[5]);  pswap(a, b);
      c = cvtpk(p1[2],  p1[3]);  d = cvtpk(p1[6],  p1[7]);  pswap(c, d);
      pf[2] = __builtin_bit_cast(bf16x8, (u32x4){a, c, b, d});
      a = cvtpk(p1[8],  p1[9]);  b = cvtpk(p1[12], p1[13]); pswap(a, b);
      c = cvtpk(p1[10], p1[11]); d = cvtpk(p1[14], p1[15]); pswap(c, d);
      pf[3] = __builtin_bit_cast(bf16x8, (u32x4){a, c, b, d});
    }
    // ---- PV: O^T += V^T * P ----
#pragma unroll
    for (int ks = 0; ks < 4; ++ks) {
      o0 = __builtin_amdgcn_mfma_f32_32x32x16_bf16(vf0[ks], pf[ks], o0, 0, 0, 0);
      o1 = __builtin_amdgcn_mfma_f32_32x32x16_bf16(vf1[ks], pf[ks], o1, 0, 0, 0);
    }
  }

  // ---- epilogue: O / l, write bf16 [B,S,H*Dh] ----
  const float rl = __builtin_amdgcn_rcpf(l);
  const int b = bh >> 3, h = bh & 7;
  const int srow = qblk*128 + w*32 + lo5;
  ushort_t* ob = ao + ((size_t)(b*NS + srow)) * ND + h*DH;
#pragma unroll
  for (int dt = 0; dt < 2; ++dt) {
    f32x16& oo = dt ? o1 : o0;
#pragma unroll
    for (int r = 0; r < 16; r += 2) {
      const int d = (r & 3) + 8*(r >> 2) + 4*hi + dt*32;
      *(uint_t*)(ob + d) = cvtpk(oo[r]*rl, oo[r+1]*rl);
    }
  }
}

extern "C" void kernel_launch(void* const* d_in, const int* in_sizes, int n_in,
                              void* d_out, int out_size, void* d_ws, size_t ws_size,
                              hipStream_t stream)
{
  const float* x  = (const float*)d_in[0];
  const float* g  = (const float*)d_in[1];
  const float* be = (const float*)d_in[2];
  const float* Wq = (const float*)d_in[3];
  const float* bq = (const float*)d_in[4];
  const float* Wk = (const float*)d_in[5];
  const float* bk = (const float*)d_in[6];
  const float* Wv = (const float*)d_in[7];
  const float* bv = (const float*)d_in[8];
  const float* Wo = (const float*)d_in[9];
  const float* bo = (const float*)d_in[10];
  float* out = (float*)d_out;

  char* w = (char*)d_ws;
  ushort_t* xn   = (ushort_t*)w; w += (size_t)MTOK*ND*2;
  ushort_t* wqkv = (ushort_t*)w; w += (size_t)1536*512*2;
  ushort_t* wob  = (ushort_t*)w; w += (size_t)512*512*2;
  ushort_t* qa   = (ushort_t*)w; w += (size_t)MTOK*ND*2;
  ushort_t* ka   = (ushort_t*)w; w += (size_t)MTOK*ND*2;
  ushort_t* vta  = (ushort_t*)w; w += (size_t)MTOK*ND*2;
  ushort_t* ao   = (ushort_t*)w; w += (size_t)MTOK*ND*2;

  ln_kernel<<<MTOK/4, 256, 0, stream>>>(x, g, be, xn);
  convert_w<<<512, 256, 0, stream>>>(Wq, Wk, Wv, Wo, wqkv, wob);
  gemm_bt<0><<<dim3(12, 64), 256, 0, stream>>>(xn, wqkv, ND,
      bq, bk, bv, qa, ka, vta, nullptr, nullptr);
  attn_kernel<<<512, 256, 0, stream>>>(qa, ka, vta, ao);
  gemm_bt<1><<<dim3(4, 64), 256, 0, stream>>>(ao, wob, ND,
      nullptr, nullptr, nullptr, nullptr, nullptr, nullptr, bo, out);
}